// Round 6
// baseline (38.389 us; speedup 1.0000x reference)
//
#include <hip/hip_runtime.h>

// Exact-rounding 3-component squared sum in reference order: (x*x + y*y) + z*z
static __device__ __forceinline__ float sq3(float x, float y, float z) {
    return __fadd_rn(__fadd_rn(__fmul_rn(x, x), __fmul_rn(y, y)), __fmul_rn(z, z));
}

// ---------------- Kernel 1: per-row H_i + packed gather table ----------------
// T[2*row]   = (Cjx, Cjy, Cjz, Ojx)
// T[2*row+1] = (Ojy, Ojz, asfloat(C[row]), 0)
__global__ __launch_bounds__(256) void setup_kernel(
    const float* __restrict__ X,
    const int*   __restrict__ C,
    float*  __restrict__ outH,
    float4* __restrict__ T,        // may be null (fallback mode)
    int N, int rows)
{
    const float EPS   = 0.001f;
    const float LENNH = 1.015f;

    int row = blockIdx.x * blockDim.x + threadIdx.x;
    if (row >= rows) return;
    int i = row & (N - 1);

    const float* xi = X + (size_t)row * 12;
    float4 a4  = *(const float4*)xi;        // N.xyz, Ca.x
    float2 a2  = *(const float2*)(xi + 4);  // Ca.y, Ca.z
    float2 c01 = *(const float2*)(xi + 6);  // C.x, C.y
    float4 co  = *(const float4*)(xi + 8);  // C.z, O.xyz
    float nx = a4.x, ny = a4.y, nz = a4.z;
    float cax = a4.w, cay = a2.x, caz = a2.y;

    if (T) {
        T[2 * (size_t)row]     = make_float4(c01.x, c01.y, co.x, co.y);
        T[2 * (size_t)row + 1] = make_float4(co.z, co.w, __int_as_float(C[row]), 0.0f);
    }

    int prow = (i == 0) ? row : row - 1;
    const float* xp = X + (size_t)prow * 12;
    float2 p2 = *(const float2*)(xp + 6);
    float px = p2.x, py = p2.y, pz = xp[8];

    // u1 = normed(N - Cprev)
    float ax = __fsub_rn(nx, px), ay = __fsub_rn(ny, py), az = __fsub_rn(nz, pz);
    float s1 = __fsqrt_rn(__fadd_rn(sq3(ax, ay, az), EPS));
    ax = __fdiv_rn(ax, s1); ay = __fdiv_rn(ay, s1); az = __fdiv_rn(az, s1);
    // u2 = normed(N - Ca)
    float bx = __fsub_rn(nx, cax), by = __fsub_rn(ny, cay), bz = __fsub_rn(nz, caz);
    float s2 = __fsqrt_rn(__fadd_rn(sq3(bx, by, bz), EPS));
    bx = __fdiv_rn(bx, s2); by = __fdiv_rn(by, s2); bz = __fdiv_rn(bz, s2);
    // u = normed(u1 + u2)
    float ux = __fadd_rn(ax, bx), uy = __fadd_rn(ay, by), uz = __fadd_rn(az, bz);
    float s3 = __fsqrt_rn(__fadd_rn(sq3(ux, uy, uz), EPS));
    ux = __fdiv_rn(ux, s3); uy = __fdiv_rn(uy, s3); uz = __fdiv_rn(uz, s3);

    float* ho = outH + (size_t)row * 3;
    ho[0] = __fadd_rn(nx, __fmul_rn(LENNH, ux));
    ho[1] = __fadd_rn(ny, __fmul_rn(LENNH, uy));
    ho[2] = __fadd_rn(nz, __fmul_rn(LENNH, uz));
}

// Per-edge math, bit-exact reference order.
static __device__ __forceinline__ void edge_math(
    float nx, float ny, float nz, float hx, float hy, float hz,
    int Ci, int i, int j, float mij, float4 t0, float4 t1,
    float& hb, float& mhb)
{
    const float EPS   = 0.001f;
    const float COEFF = (float)(0.42 * 0.2 * 332.0);   // 27.888f

    float cjx = t0.x, cjy = t0.y, cjz = t0.z;
    float ojx = t0.w, ojy = t1.x, ojz = t1.y;
    int   Cn  = __float_as_int(t1.z);

    float dx = __fsub_rn(nx, ojx), dy = __fsub_rn(ny, ojy), dz = __fsub_rn(nz, ojz);
    float dno = __fsqrt_rn(__fadd_rn(sq3(dx, dy, dz), EPS));
    float iNO = __fdiv_rn(1.0f, dno);
    dx = __fsub_rn(nx, cjx); dy = __fsub_rn(ny, cjy); dz = __fsub_rn(nz, cjz);
    float iNC = __fdiv_rn(1.0f, __fsqrt_rn(__fadd_rn(sq3(dx, dy, dz), EPS)));
    dx = __fsub_rn(hx, cjx); dy = __fsub_rn(hy, cjy); dz = __fsub_rn(hz, cjz);
    float iHC = __fdiv_rn(1.0f, __fsqrt_rn(__fadd_rn(sq3(dx, dy, dz), EPS)));
    dx = __fsub_rn(hx, ojx); dy = __fsub_rn(hy, ojy); dz = __fsub_rn(hz, ojz);
    float iHO = __fdiv_rn(1.0f, __fsqrt_rn(__fadd_rn(sq3(dx, dy, dz), EPS)));

    float U = __fmul_rn(COEFF, __fsub_rn(__fadd_rn(__fsub_rn(iNO, iNC), iHC), iHO));

    int dij = j - i; if (dij < 0) dij = -dij;
    float m_local    = ((dij < 3) && (Ci == Cn)) ? 1.0f : 0.0f;
    float m_nonlocal = __fsub_rn(1.0f, m_local);
    float m_cutD     = (dno < 3.6f) ? 1.0f : 0.0f;
    float m_i        = (Ci > 0) ? 1.0f : 0.0f;
    float m_int      = __fmul_rn(m_i, (Cn > 0) ? 1.0f : 0.0f);

    mhb = __fmul_rn(__fmul_rn(__fmul_rn(mij, m_nonlocal), m_cutD), m_int);
    hb  = __fmul_rn(mhb, (U < -0.5f) ? 1.0f : 0.0f);
}

static __device__ __forceinline__ float4 swapx1(float4 v) {
    float4 r;
    r.x = __shfl_xor(v.x, 1, 64);
    r.y = __shfl_xor(v.y, 1, 64);
    r.z = __shfl_xor(v.z, 1, 64);
    r.w = __shfl_xor(v.w, 1, 64);
    return r;
}

// ------- Kernel 2: persistent waves, 2-row ILP, pair-gather, no j/m shuffles -------
// Each wave owns `rpw` consecutive rows; the loop body processes 2 rows.
// Per row: lanes 2e,2e+1 cooperatively fetch edge entries (1 x 64-B line/edge):
//   round 0: lane loads half (lane&1)   of edge e       (j from E[base+e], pair-broadcast)
//   round 1: lane loads half (lane&1)^1 of edge 32+e    (j from E[base+32+e])
// One shfl_xor(1) per round completes each lane's 32-B entry; even lanes then
// own edge e, odd lanes edge 32+e. M and stores use the permuted offset
// eM = (half<<5)|e directly (full line coverage, no reorder shuffles).
__global__ __launch_bounds__(256) void edge_kernel_ilp(
    const int*   __restrict__ C,
    const int*   __restrict__ E,
    const float* __restrict__ M,
    const float* __restrict__ H,
    const float* __restrict__ X,
    const float4* __restrict__ T,
    float* __restrict__ outHB,
    float* __restrict__ outMK,
    int N, int rows, int rpw)
{
    int gtid = blockIdx.x * blockDim.x + threadIdx.x;
    int wave = __builtin_amdgcn_readfirstlane(gtid >> 6);
    int lane = threadIdx.x & 63;
    int e    = lane >> 1;
    int half = lane & 1;
    int eM   = (half << 5) | e;

    int base_row = wave * rpw;
    if (base_row >= rows) return;

    for (int t = 0; t < rpw; t += 2) {
        int rowA = base_row + t;
        if (rowA >= rows) break;
        int rowB = rowA + 1;           // rows and rpw are even
        int iA = rowA & (N - 1), iB = rowB & (N - 1);
        const float4* TbA = T + ((size_t)(rowA >> 14) << 15);
        const float4* TbB = T + ((size_t)(rowB >> 14) << 15);

        size_t bA = (size_t)rowA << 6;
        size_t bB = (size_t)rowB << 6;

        // direct j loads (2 lanes/address), then gathers — no ds hop in the chain
        int jA0 = E[bA + e];
        int jA1 = E[bA + 32 + e];
        int jB0 = E[bB + e];
        int jB1 = E[bB + 32 + e];
        float mMA = M[bA + eM];
        float mMB = M[bB + eM];

        float4 vA0 = TbA[2 * (size_t)jA0 + half];
        float4 vA1 = TbA[2 * (size_t)jA1 + (half ^ 1)];
        float4 vB0 = TbB[2 * (size_t)jB0 + half];
        float4 vB1 = TbB[2 * (size_t)jB1 + (half ^ 1)];

        // wave-uniform row data (scalar loads)
        const float* xiA = X + (size_t)rowA * 12;
        const float* hiA = H + (size_t)rowA * 3;
        const float* xiB = X + (size_t)rowB * 12;
        const float* hiB = H + (size_t)rowB * 3;
        float nxA = xiA[0], nyA = xiA[1], nzA = xiA[2];
        float hxA = hiA[0], hyA = hiA[1], hzA = hiA[2];
        float nxB = xiB[0], nyB = xiB[1], nzB = xiB[2];
        float hxB = hiB[0], hyB = hiB[1], hzB = hiB[2];
        int CiA = C[rowA], CiB = C[rowB];

        float4 wA0 = swapx1(vA0), wA1 = swapx1(vA1);
        float4 wB0 = swapx1(vB0), wB1 = swapx1(vB1);

        float4 t0A = half ? vA1 : vA0;
        float4 t1A = half ? wA1 : wA0;
        float4 t0B = half ? vB1 : vB0;
        float4 t1B = half ? wB1 : wB0;
        int jMA = half ? jA1 : jA0;
        int jMB = half ? jB1 : jB0;

        float hbA, mkA, hbB, mkB;
        edge_math(nxA, nyA, nzA, hxA, hyA, hzA, CiA, iA, jMA, mMA, t0A, t1A, hbA, mkA);
        edge_math(nxB, nyB, nzB, hxB, hyB, hzB, CiB, iB, jMB, mMB, t0B, t1B, hbB, mkB);

        outHB[bA + eM] = hbA;
        outMK[bA + eM] = mkA;
        outHB[bB + eM] = hbB;
        outMK[bB + eM] = mkB;
    }
}

// ---------------- Fallback kernel (no workspace): R2 path, known-good ----------------
__global__ __launch_bounds__(256) void edge_kernel_noT(
    const float* __restrict__ X,
    const int*   __restrict__ C,
    const int*   __restrict__ E,
    const float* __restrict__ M,
    const float* __restrict__ H,
    float* __restrict__ outHB,
    float* __restrict__ outMK,
    int N, int rows)
{
    int tid = blockIdx.x * blockDim.x + threadIdx.x;
    int row = tid >> 6;
    if (row >= rows) return;
    int k = tid & 63;
    int i = row & (N - 1);
    int b = row >> 14;

    int urow = __builtin_amdgcn_readfirstlane(row);
    const float* xi = X + (size_t)urow * 12;
    float nx = xi[0], ny = xi[1], nz = xi[2];
    const float* hi = H + (size_t)urow * 3;
    float hx = hi[0], hy = hi[1], hz = hi[2];
    int Ci = C[urow];

    size_t eoff = (size_t)row * 64 + (size_t)k;
    int j = E[eoff];
    float mij = M[eoff];

    const float* xj = X + ((size_t)b * (size_t)N + (size_t)j) * 12;
    float2 cj01 = *(const float2*)(xj + 6);
    float4 v4   = *(const float4*)(xj + 8);
    int Cn = C[(size_t)b * (size_t)N + (size_t)j];

    float4 t0 = make_float4(cj01.x, cj01.y, v4.x, v4.y);
    float4 t1 = make_float4(v4.z, v4.w, __int_as_float(Cn), 0.0f);
    float hb, mhb;
    edge_math(nx, ny, nz, hx, hy, hz, Ci, i, j, mij, t0, t1, hb, mhb);

    outHB[eoff] = hb;
    outMK[eoff] = mhb;
}

extern "C" void kernel_launch(void* const* d_in, const int* in_sizes, int n_in,
                              void* d_out, int out_size, void* d_ws, size_t ws_size,
                              hipStream_t stream) {
    const float* X = (const float*)d_in[0];
    const int*   C = (const int*)d_in[1];
    const int*   E = (const int*)d_in[2];
    const float* M = (const float*)d_in[3];

    int rows = in_sizes[1];          // B*N = 65536
    int BNK  = in_sizes[2];          // B*N*K
    const int N = 16384;

    float* out   = (float*)d_out;
    float* outHB = out;
    float* outMK = out + (size_t)BNK;
    float* outH  = out + 2 * (size_t)BNK;

    size_t tbytes = (size_t)rows * 32;
    bool useT = (ws_size >= tbytes) && (d_ws != nullptr);
    float4* T = useT ? (float4*)d_ws : nullptr;

    {
        int block = 256;
        int grid  = (rows + block - 1) / block;
        hipLaunchKernelGGL(setup_kernel, dim3(grid), dim3(block), 0, stream,
                           X, C, outH, T, N, rows);
    }
    if (useT) {
        // target ~8192 waves (32 waves/CU); rpw even
        int target_waves = 8192;
        int rpw = (rows + target_waves - 1) / target_waves;
        if (rpw & 1) rpw++;
        if (rpw < 2) rpw = 2;
        int waves = (rows + rpw - 1) / rpw;
        int total = waves * 64;
        int block = 256;
        int grid  = (total + block - 1) / block;
        hipLaunchKernelGGL(edge_kernel_ilp, dim3(grid), dim3(block), 0, stream,
                           C, E, M, outH, X, T, outHB, outMK, N, rows, rpw);
    } else {
        int total = rows * 64;
        int block = 256;
        int grid  = (total + block - 1) / block;
        hipLaunchKernelGGL(edge_kernel_noT, dim3(grid), dim3(block), 0, stream,
                           X, C, E, M, outH, outHB, outMK, N, rows);
    }
}

// Round 8
// 34.644 us; speedup vs baseline: 1.1081x; 1.1081x over previous
//
#include <hip/hip_runtime.h>

// Exact-rounding 3-component squared sum in reference order: (x*x + y*y) + z*z
static __device__ __forceinline__ float sq3(float x, float y, float z) {
    return __fadd_rn(__fadd_rn(__fmul_rn(x, x), __fmul_rn(y, y)), __fmul_rn(z, z));
}

// ---------------- Kernel 1: per-row H_i + packed gather table ----------------
// T[2*row]   = (Cjx, Cjy, Cjz, Ojx)
// T[2*row+1] = (Ojy, Ojz, asfloat(C[row]), 0)
__global__ __launch_bounds__(256) void setup_kernel(
    const float* __restrict__ X,
    const int*   __restrict__ C,
    float*  __restrict__ outH,
    float4* __restrict__ T,        // may be null (fallback mode)
    int N, int rows)
{
    const float EPS   = 0.001f;
    const float LENNH = 1.015f;

    int row = blockIdx.x * blockDim.x + threadIdx.x;
    if (row >= rows) return;
    int i = row & (N - 1);

    const float* xi = X + (size_t)row * 12;
    float4 a4  = *(const float4*)xi;        // N.xyz, Ca.x
    float2 a2  = *(const float2*)(xi + 4);  // Ca.y, Ca.z
    float2 c01 = *(const float2*)(xi + 6);  // C.x, C.y
    float4 co  = *(const float4*)(xi + 8);  // C.z, O.xyz
    float nx = a4.x, ny = a4.y, nz = a4.z;
    float cax = a4.w, cay = a2.x, caz = a2.y;

    if (T) {
        T[2 * (size_t)row]     = make_float4(c01.x, c01.y, co.x, co.y);
        T[2 * (size_t)row + 1] = make_float4(co.z, co.w, __int_as_float(C[row]), 0.0f);
    }

    int prow = (i == 0) ? row : row - 1;
    const float* xp = X + (size_t)prow * 12;
    float2 p2 = *(const float2*)(xp + 6);
    float px = p2.x, py = p2.y, pz = xp[8];

    // u1 = normed(N - Cprev)
    float ax = __fsub_rn(nx, px), ay = __fsub_rn(ny, py), az = __fsub_rn(nz, pz);
    float s1 = __fsqrt_rn(__fadd_rn(sq3(ax, ay, az), EPS));
    ax = __fdiv_rn(ax, s1); ay = __fdiv_rn(ay, s1); az = __fdiv_rn(az, s1);
    // u2 = normed(N - Ca)
    float bx = __fsub_rn(nx, cax), by = __fsub_rn(ny, cay), bz = __fsub_rn(nz, caz);
    float s2 = __fsqrt_rn(__fadd_rn(sq3(bx, by, bz), EPS));
    bx = __fdiv_rn(bx, s2); by = __fdiv_rn(by, s2); bz = __fdiv_rn(bz, s2);
    // u = normed(u1 + u2)
    float ux = __fadd_rn(ax, bx), uy = __fadd_rn(ay, by), uz = __fadd_rn(az, bz);
    float s3 = __fsqrt_rn(__fadd_rn(sq3(ux, uy, uz), EPS));
    ux = __fdiv_rn(ux, s3); uy = __fdiv_rn(uy, s3); uz = __fdiv_rn(uz, s3);

    float* ho = outH + (size_t)row * 3;
    ho[0] = __fadd_rn(nx, __fmul_rn(LENNH, ux));
    ho[1] = __fadd_rn(ny, __fmul_rn(LENNH, uy));
    ho[2] = __fadd_rn(nz, __fmul_rn(LENNH, uz));
}

// Per-edge math, bit-exact reference order.
static __device__ __forceinline__ void edge_math(
    float nx, float ny, float nz, float hx, float hy, float hz,
    int Ci, int i, int j, float mij, float4 t0, float4 t1,
    float& hb, float& mhb)
{
    const float EPS   = 0.001f;
    const float COEFF = (float)(0.42 * 0.2 * 332.0);   // 27.888f

    float cjx = t0.x, cjy = t0.y, cjz = t0.z;
    float ojx = t0.w, ojy = t1.x, ojz = t1.y;
    int   Cn  = __float_as_int(t1.z);

    float dx = __fsub_rn(nx, ojx), dy = __fsub_rn(ny, ojy), dz = __fsub_rn(nz, ojz);
    float dno = __fsqrt_rn(__fadd_rn(sq3(dx, dy, dz), EPS));
    float iNO = __fdiv_rn(1.0f, dno);
    dx = __fsub_rn(nx, cjx); dy = __fsub_rn(ny, cjy); dz = __fsub_rn(nz, cjz);
    float iNC = __fdiv_rn(1.0f, __fsqrt_rn(__fadd_rn(sq3(dx, dy, dz), EPS)));
    dx = __fsub_rn(hx, cjx); dy = __fsub_rn(hy, cjy); dz = __fsub_rn(hz, cjz);
    float iHC = __fdiv_rn(1.0f, __fsqrt_rn(__fadd_rn(sq3(dx, dy, dz), EPS)));
    dx = __fsub_rn(hx, ojx); dy = __fsub_rn(hy, ojy); dz = __fsub_rn(hz, ojz);
    float iHO = __fdiv_rn(1.0f, __fsqrt_rn(__fadd_rn(sq3(dx, dy, dz), EPS)));

    float U = __fmul_rn(COEFF, __fsub_rn(__fadd_rn(__fsub_rn(iNO, iNC), iHC), iHO));

    int dij = j - i; if (dij < 0) dij = -dij;
    float m_local    = ((dij < 3) && (Ci == Cn)) ? 1.0f : 0.0f;
    float m_nonlocal = __fsub_rn(1.0f, m_local);
    float m_cutD     = (dno < 3.6f) ? 1.0f : 0.0f;
    float m_i        = (Ci > 0) ? 1.0f : 0.0f;
    float m_int      = __fmul_rn(m_i, (Cn > 0) ? 1.0f : 0.0f);

    mhb = __fmul_rn(__fmul_rn(__fmul_rn(mij, m_nonlocal), m_cutD), m_int);
    hb  = __fmul_rn(mhb, (U < -0.5f) ? 1.0f : 0.0f);
}

static __device__ __forceinline__ float4 swapx1(float4 v) {
    float4 r;
    r.x = __shfl_xor(v.x, 1, 64);
    r.y = __shfl_xor(v.y, 1, 64);
    r.z = __shfl_xor(v.z, 1, 64);
    r.w = __shfl_xor(v.w, 1, 64);
    return r;
}

// ------- Kernel 2: 1 row/wave, pair-gather, XCD-batch-affinity swizzle -------
// Lanes 2e,2e+1 cooperatively fetch each 32-B table entry (one 64-B line/edge):
//   lane loads half (lane&1)   of edge e        (j pair-broadcast from E[base+e])
//   lane loads half (lane&1)^1 of edge 32+e
// One shfl_xor(1) per round completes the entry; even lanes own edge e, odd
// lanes edge 32+e. M load and stores use eM=(half<<5)|e (full line coverage).
// Block swizzle (B==4): XCD g%8 -> batch (g%8)>>1, so each XCD gathers only
// its batch's 2-MB T slice (fits 4-MB L2). Plain loads/stores only —
// nontemporal builtins caused a post-timing coherence failure in R7.
__global__ __launch_bounds__(256) void edge_kernel_swz(
    const int*   __restrict__ C,
    const int*   __restrict__ E,
    const float* __restrict__ M,
    const float* __restrict__ H,
    const float* __restrict__ X,
    const float4* __restrict__ T,
    float* __restrict__ outHB,
    float* __restrict__ outMK,
    int N, int rows, int swz)
{
    int g = blockIdx.x;
    int row0;
    if (swz) {
        int b = (g & 7) >> 1;                    // batch for this XCD pair
        int o = ((g >> 3) << 1) | (g & 1);       // block ordinal within batch
        row0 = b * N + (o << 2);                 // 4 rows per block
    } else {
        row0 = g << 2;
    }
    int row = row0 + (int)(threadIdx.x >> 6);
    if (row >= rows) return;
    int lane = threadIdx.x & 63;
    int e    = lane >> 1;
    int half = lane & 1;
    int eM   = (half << 5) | e;
    int i = row & (N - 1);

    int urow = __builtin_amdgcn_readfirstlane(row);
    const float* xi = X + (size_t)urow * 12;
    float nx = xi[0], ny = xi[1], nz = xi[2];
    const float* hi = H + (size_t)urow * 3;
    float hx = hi[0], hy = hi[1], hz = hi[2];
    int Ci = C[urow];

    size_t base = (size_t)row << 6;

    // direct j loads (2 lanes/address) and per-lane M load
    int   jA = E[base + e];
    int   jB = E[base + 32 + e];
    float mM = M[base + eM];

    const float4* Tb = T + ((size_t)(row >> 14) << 15);   // 2*N float4 per batch
    // both gathers issued up front; each pair hits one 64-B line
    float4 vA = Tb[2 * (size_t)jA + half];
    float4 vB = Tb[2 * (size_t)jB + (half ^ 1)];

    float4 wA = swapx1(vA);
    float4 wB = swapx1(vB);

    // even lanes own edge e (t0=vA,t1=wA); odd lanes edge 32+e (t0=vB,t1=wB)
    float4 t0 = half ? vB : vA;
    float4 t1 = half ? wB : wA;
    int jMine = half ? jB : jA;

    float hb, mk;
    edge_math(nx, ny, nz, hx, hy, hz, Ci, i, jMine, mM, t0, t1, hb, mk);

    outHB[base + eM] = hb;
    outMK[base + eM] = mk;
}

// ---------------- Fallback kernel (no workspace): R2 path, known-good ----------------
__global__ __launch_bounds__(256) void edge_kernel_noT(
    const float* __restrict__ X,
    const int*   __restrict__ C,
    const int*   __restrict__ E,
    const float* __restrict__ M,
    const float* __restrict__ H,
    float* __restrict__ outHB,
    float* __restrict__ outMK,
    int N, int rows)
{
    int tid = blockIdx.x * blockDim.x + threadIdx.x;
    int row = tid >> 6;
    if (row >= rows) return;
    int k = tid & 63;
    int i = row & (N - 1);
    int b = row >> 14;

    int urow = __builtin_amdgcn_readfirstlane(row);
    const float* xi = X + (size_t)urow * 12;
    float nx = xi[0], ny = xi[1], nz = xi[2];
    const float* hi = H + (size_t)urow * 3;
    float hx = hi[0], hy = hi[1], hz = hi[2];
    int Ci = C[urow];

    size_t eoff = (size_t)row * 64 + (size_t)k;
    int j = E[eoff];
    float mij = M[eoff];

    const float* xj = X + ((size_t)b * (size_t)N + (size_t)j) * 12;
    float2 cj01 = *(const float2*)(xj + 6);
    float4 v4   = *(const float4*)(xj + 8);
    int Cn = C[(size_t)b * (size_t)N + (size_t)j];

    float4 t0 = make_float4(cj01.x, cj01.y, v4.x, v4.y);
    float4 t1 = make_float4(v4.z, v4.w, __int_as_float(Cn), 0.0f);
    float hb, mhb;
    edge_math(nx, ny, nz, hx, hy, hz, Ci, i, j, mij, t0, t1, hb, mhb);

    outHB[eoff] = hb;
    outMK[eoff] = mhb;
}

extern "C" void kernel_launch(void* const* d_in, const int* in_sizes, int n_in,
                              void* d_out, int out_size, void* d_ws, size_t ws_size,
                              hipStream_t stream) {
    const float* X = (const float*)d_in[0];
    const int*   C = (const int*)d_in[1];
    const int*   E = (const int*)d_in[2];
    const float* M = (const float*)d_in[3];

    int rows = in_sizes[1];          // B*N = 65536
    int BNK  = in_sizes[2];          // B*N*K
    const int N = 16384;
    int B = rows / N;

    float* out   = (float*)d_out;
    float* outHB = out;
    float* outMK = out + (size_t)BNK;
    float* outH  = out + 2 * (size_t)BNK;

    size_t tbytes = (size_t)rows * 32;
    bool useT = (ws_size >= tbytes) && (d_ws != nullptr);
    float4* T = useT ? (float4*)d_ws : nullptr;

    {
        int block = 256;
        int grid  = (rows + block - 1) / block;
        hipLaunchKernelGGL(setup_kernel, dim3(grid), dim3(block), 0, stream,
                           X, C, outH, T, N, rows);
    }
    if (useT) {
        // 4 rows (waves) per block; XCD-affinity swizzle valid when B==4 and
        // block count is a multiple of 8.
        int grid = (rows + 3) / 4;
        int swz  = (B == 4 && (grid % 8 == 0)) ? 1 : 0;
        hipLaunchKernelGGL(edge_kernel_swz, dim3(grid), dim3(256), 0, stream,
                           C, E, M, outH, X, T, outHB, outMK, N, rows, swz);
    } else {
        int total = rows * 64;
        int block = 256;
        int grid  = (total + block - 1) / block;
        hipLaunchKernelGGL(edge_kernel_noT, dim3(grid), dim3(block), 0, stream,
                           X, C, E, M, outH, outHB, outMK, N, rows);
    }
}